// Round 4
// baseline (3799.786 us; speedup 1.0000x reference)
//
#include <hip/hip_runtime.h>
#include <math.h>

#define B_  1024
#define T_  512
#define D_  30
#define H1_ 96
#define G1_ 384
#define H2_ 64
#define G2_ 256

// Inter-kernel buffers as device globals (.bss, bound at module load).
__device__ float g_h1[(size_t)B_ * T_ * 192];   // 384 MiB: layer-1 output
__device__ float g_h2f[(size_t)B_ * H2_];       // layer-2 fwd final state

__device__ __forceinline__ float fast_tanh(float v) {
  float a = fabsf(v);
  float e = __expf(-2.0f * a);
  float t = 1.0f - 2.0f * e / (1.0f + e);
  return v < 0.0f ? -t : t;
}
__device__ __forceinline__ float fast_sigmoid(float v) {
  return 0.5f + 0.5f * fast_tanh(0.5f * v);   // exact identity, overflow-safe
}

#define FMAROW(a_, w_, v_)                                                    \
  a_ = fmaf(w_.x, v_.x, a_); a_ = fmaf(w_.y, v_.y, a_);                       \
  a_ = fmaf(w_.z, v_.z, a_); a_ = fmaf(w_.w, v_.w, a_);

// Barrier with LDS-only drain (skips vmcnt: g_h1 stores + x prefetch stay
// in flight across steps).
#define BAR_LGKM() do {                                                       \
    asm volatile("s_waitcnt lgkmcnt(0)" ::: "memory");                        \
    __builtin_amdgcn_s_barrier();                                             \
    asm volatile("" ::: "memory");                                            \
  } while (0)

// ---------------------------------------------------------------------------
// Layer 1: bidirectional LSTM over x (B,T,30) -> g_h1 (B,T,192)
// grid (128, 2). 768 threads, TRANSPOSED layout: tid = j*8 + e
// (j = unit 0..95 owning gate rows j,j+96,j+192,j+288; e = k-chunk 0..7 of
// 16 k). All 8 chunk-partials of a unit live in ONE wave -> gate reduction is
// wave-internal (per-wave LDS scratch + lgkmcnt, NO barrier). hx is
// double-buffered & chunk-major [c][b][16] (stride 132) -> ONE barrier/step
// and conflict-free b128 FMA reads.
// v[128]: chunks 0-1 = x_t (30 + 2 zero-pad), chunks 2-7 = h_{t-1}.
// ---------------------------------------------------------------------------
__global__ __launch_bounds__(768, 4)
void lstm1_kernel(const float* __restrict__ x,
                  const float* __restrict__ Wih_f, const float* __restrict__ Whh_f,
                  const float* __restrict__ bih_f, const float* __restrict__ bhh_f,
                  const float* __restrict__ Wih_b, const float* __restrict__ Whh_b,
                  const float* __restrict__ bih_b, const float* __restrict__ bhh_b)
{
  const int tid = threadIdx.x;
  const int dir = blockIdx.y;
  const int b0  = blockIdx.x * 8;

  const float* __restrict__ Wih = dir ? Wih_b : Wih_f;
  const float* __restrict__ Whh = dir ? Whh_b : Whh_f;
  const float* __restrict__ bih = dir ? bih_b : bih_f;
  const float* __restrict__ bhh = dir ? bhh_b : bhh_f;

  const int j  = tid >> 3;                       // unit 0..95
  const int e  = tid & 7;                        // k-chunk 0..7
  const int wv = tid >> 6;                       // wave 0..11
  const int jl = j & 7;                          // unit-in-wave 0..7

  // hx: [2 buf][8 chunks][8 b * 16 + 4 pad = 132]  (8.4 KB)
  __shared__ __align__(16) float hxs[2 * 1056];
  // scratch: per-wave [8 jl][8 e'][8 b] float4(4 gates); jl-stride 65 f4
  // (odd -> writes/reads at LDS BW floor, no super-linear conflicts)
  __shared__ float4 scr4[12 * 520];              // 99.8 KB

  // 16 NAMED float4 regs: 4 gate rows x 4 float4 over k in [16e, 16e+16).
  float4 wA0,wA1,wA2,wA3, wB0,wB1,wB2,wB3, wC0,wC1,wC2,wC3, wD0,wD1,wD2,wD3;
  if (e < 2) {                                   // k = 0..31: x-part (30 + 2 pad)
    const int k0 = e * 16;
#define LDXF(r_, kk) (((kk) < D_) ? Wih[(r_) * D_ + (kk)] : 0.0f)
#define LW4(d0,d1,d2,d3, r_) {                                                \
    d0 = make_float4(LDXF(r_,k0+ 0),LDXF(r_,k0+ 1),LDXF(r_,k0+ 2),LDXF(r_,k0+ 3)); \
    d1 = make_float4(LDXF(r_,k0+ 4),LDXF(r_,k0+ 5),LDXF(r_,k0+ 6),LDXF(r_,k0+ 7)); \
    d2 = make_float4(LDXF(r_,k0+ 8),LDXF(r_,k0+ 9),LDXF(r_,k0+10),LDXF(r_,k0+11)); \
    d3 = make_float4(LDXF(r_,k0+12),LDXF(r_,k0+13),LDXF(r_,k0+14),LDXF(r_,k0+15)); }
    LW4(wA0,wA1,wA2,wA3, j      )
    LW4(wB0,wB1,wB2,wB3, j +  96)
    LW4(wC0,wC1,wC2,wC3, j + 192)
    LW4(wD0,wD1,wD2,wD3, j + 288)
#undef LW4
#undef LDXF
  } else {                                       // k = 16e..16e+15: h-part
    const int c0 = e * 16 - 32;
    const float4* pA = (const float4*)(Whh + (j      ) * H1_ + c0);
    const float4* pB = (const float4*)(Whh + (j +  96) * H1_ + c0);
    const float4* pC = (const float4*)(Whh + (j + 192) * H1_ + c0);
    const float4* pD = (const float4*)(Whh + (j + 288) * H1_ + c0);
    wA0=pA[0]; wA1=pA[1]; wA2=pA[2]; wA3=pA[3];
    wB0=pB[0]; wB1=pB[1]; wB2=pB[2]; wB3=pB[3];
    wC0=pC[0]; wC1=pC[1]; wC2=pC[2]; wC3=pC[3];
    wD0=pD[0]; wD1=pD[1]; wD2=pD[2]; wD3=pD[3];
  }

  const float bias_i = bih[j      ] + bhh[j      ];
  const float bias_f = bih[j +  96] + bhh[j +  96];
  const float bias_g = bih[j + 192] + bhh[j + 192];
  const float bias_o = bih[j + 288] + bhh[j + 288];
  float c_state = 0.0f;

  for (int i = tid; i < 2 * 1056; i += 768) hxs[i] = 0.0f;
  __syncthreads();
  const int xb = tid / 30;                       // x stagers: tid < 240
  const int xd = tid - xb * 30;
  const int xoff = 132 * (xd >> 4) + 16 * xb + (xd & 15);
  if (tid < 240) {
    const int t0 = dir ? (T_ - 1) : 0;
    hxs[xoff] = x[((size_t)(b0 + xb) * T_ + t0) * D_ + xd];
  }
  __syncthreads();

  const int ef = 33 * e;                         // f4 base of my k-chunk
  float4* scrw = scr4 + wv * 520 + jl * 65;      // shared write/read base
  const int we8 = e * 8;
  const int hoff = 132 * (2 + (j >> 4)) + 16 * e + ((32 + j) & 15);
  float* __restrict__ gp = g_h1 + ((size_t)(b0 + e) * T_) * 192
                                + (size_t)dir * 96 + j;

  for (int s = 0; s < T_; ++s) {
    const int t   = dir ? (T_ - 1 - s) : s;
    const int cur = s & 1, nxt = cur ^ 1;
    float xn = 0.0f;
    if (tid < 240 && s + 1 < T_) {
      const int tn = dir ? (t - 1) : (t + 1);
      xn = x[((size_t)(b0 + xb) * T_ + tn) * D_ + xd];
    }
    const float4* hb = (const float4*)(hxs + cur * 1056);
    float aI0=0.f,aI1=0.f,aI2=0.f,aI3=0.f,aI4=0.f,aI5=0.f,aI6=0.f,aI7=0.f;
    float aF0=0.f,aF1=0.f,aF2=0.f,aF3=0.f,aF4=0.f,aF5=0.f,aF6=0.f,aF7=0.f;
    float aG0=0.f,aG1=0.f,aG2=0.f,aG3=0.f,aG4=0.f,aG5=0.f,aG6=0.f,aG7=0.f;
    float aO0=0.f,aO1=0.f,aO2=0.f,aO3=0.f,aO4=0.f,aO5=0.f,aO6=0.f,aO7=0.f;
#define FB1(i) {                                                              \
    float4 v0 = hb[ef +  0 + i]; float4 v1 = hb[ef +  4 + i];                 \
    float4 v2 = hb[ef +  8 + i]; float4 v3 = hb[ef + 12 + i];                 \
    float4 v4 = hb[ef + 16 + i]; float4 v5 = hb[ef + 20 + i];                 \
    float4 v6 = hb[ef + 24 + i]; float4 v7 = hb[ef + 28 + i];                 \
    FMAROW(aI0, wA##i, v0) FMAROW(aF0, wB##i, v0)                             \
    FMAROW(aG0, wC##i, v0) FMAROW(aO0, wD##i, v0)                             \
    FMAROW(aI1, wA##i, v1) FMAROW(aF1, wB##i, v1)                             \
    FMAROW(aG1, wC##i, v1) FMAROW(aO1, wD##i, v1)                             \
    FMAROW(aI2, wA##i, v2) FMAROW(aF2, wB##i, v2)                             \
    FMAROW(aG2, wC##i, v2) FMAROW(aO2, wD##i, v2)                             \
    FMAROW(aI3, wA##i, v3) FMAROW(aF3, wB##i, v3)                             \
    FMAROW(aG3, wC##i, v3) FMAROW(aO3, wD##i, v3)                             \
    FMAROW(aI4, wA##i, v4) FMAROW(aF4, wB##i, v4)                             \
    FMAROW(aG4, wC##i, v4) FMAROW(aO4, wD##i, v4)                             \
    FMAROW(aI5, wA##i, v5) FMAROW(aF5, wB##i, v5)                             \
    FMAROW(aG5, wC##i, v5) FMAROW(aO5, wD##i, v5)                             \
    FMAROW(aI6, wA##i, v6) FMAROW(aF6, wB##i, v6)                             \
    FMAROW(aG6, wC##i, v6) FMAROW(aO6, wD##i, v6)                             \
    FMAROW(aI7, wA##i, v7) FMAROW(aF7, wB##i, v7)                             \
    FMAROW(aG7, wC##i, v7) FMAROW(aO7, wD##i, v7) }
    FB1(0) FB1(1) FB1(2) FB1(3)
#undef FB1
    // wave-internal reduction: write my 8 batch-partials, read my batch's 8
    // chunk-partials. Same wave -> lgkmcnt (compiler-inserted), no barrier.
    scrw[we8 + 0] = make_float4(aI0, aF0, aG0, aO0);
    scrw[we8 + 1] = make_float4(aI1, aF1, aG1, aO1);
    scrw[we8 + 2] = make_float4(aI2, aF2, aG2, aO2);
    scrw[we8 + 3] = make_float4(aI3, aF3, aG3, aO3);
    scrw[we8 + 4] = make_float4(aI4, aF4, aG4, aO4);
    scrw[we8 + 5] = make_float4(aI5, aF5, aG5, aO5);
    scrw[we8 + 6] = make_float4(aI6, aF6, aG6, aO6);
    scrw[we8 + 7] = make_float4(aI7, aF7, aG7, aO7);
    {
      float4 r0 = scrw[ 0 + e], r1 = scrw[ 8 + e];
      float4 r2 = scrw[16 + e], r3 = scrw[24 + e];
      float4 r4 = scrw[32 + e], r5 = scrw[40 + e];
      float4 r6 = scrw[48 + e], r7 = scrw[56 + e];
      float gi = bias_i + r0.x + r1.x + r2.x + r3.x + r4.x + r5.x + r6.x + r7.x;
      float gf = bias_f + r0.y + r1.y + r2.y + r3.y + r4.y + r5.y + r6.y + r7.y;
      float gg = bias_g + r0.z + r1.z + r2.z + r3.z + r4.z + r5.z + r6.z + r7.z;
      float go = bias_o + r0.w + r1.w + r2.w + r3.w + r4.w + r5.w + r6.w + r7.w;
      float iv = fast_sigmoid(gi);
      float fv = fast_sigmoid(gf);
      float ov = fast_sigmoid(go);
      c_state = fv * c_state + iv * fast_tanh(gg);
      float h = ov * fast_tanh(c_state);
      hxs[nxt * 1056 + hoff] = h;                // my cell = (unit j, batch e)
      gp[(size_t)t * 192] = h;
    }
    if (tid < 240 && s + 1 < T_) hxs[nxt * 1056 + xoff] = xn;
    BAR_LGKM();
  }
}

// ---------------------------------------------------------------------------
// Layer 2 forward scan: g_h1 (B,T,192) -> g_h2f (B,64).
// grid 256: 4 batch/block. 1024 threads, tid = j*16 + e (j = unit 0..63,
// e = k-chunk 0..15 of 16 k over v[256]). Wave-internal reduction; lanes
// e<4 update cell (j, batch e). hx double-buffered chunk-major
// [16 c][4 b * 16 + 4 pad = 68]; one barrier/step.
// chunks 0-11 = h1_t, 12-15 = h2_{t-1}.
// ---------------------------------------------------------------------------
__global__ __launch_bounds__(1024, 4)
void lstm2f_kernel(const float* __restrict__ Wih, const float* __restrict__ Whh,
                   const float* __restrict__ bih, const float* __restrict__ bhh)
{
  const int tid = threadIdx.x;
  const int b0  = blockIdx.x * 4;
  const int j   = tid >> 4;                      // unit 0..63
  const int e   = tid & 15;                      // k-chunk 0..15
  const int wv  = tid >> 6;                      // wave 0..15
  const int jl  = j & 3;                         // unit-in-wave 0..3

  __shared__ __align__(16) float hxs[2 * 1088];  // [2][16 c][68]  (8.7 KB)
  __shared__ float4 scr4[16 * 260];              // per-wave [4 jl][16 e'][4 b], 66.6 KB

  const int k0 = e * 16;
  float4 wA0,wA1,wA2,wA3, wB0,wB1,wB2,wB3, wC0,wC1,wC2,wC3, wD0,wD1,wD2,wD3;
  if (e < 12) {
    const float4* pA = (const float4*)(Wih + (j      ) * 192 + k0);
    const float4* pB = (const float4*)(Wih + (j +  64) * 192 + k0);
    const float4* pC = (const float4*)(Wih + (j + 128) * 192 + k0);
    const float4* pD = (const float4*)(Wih + (j + 192) * 192 + k0);
    wA0=pA[0]; wA1=pA[1]; wA2=pA[2]; wA3=pA[3];
    wB0=pB[0]; wB1=pB[1]; wB2=pB[2]; wB3=pB[3];
    wC0=pC[0]; wC1=pC[1]; wC2=pC[2]; wC3=pC[3];
    wD0=pD[0]; wD1=pD[1]; wD2=pD[2]; wD3=pD[3];
  } else {
    const int c0 = k0 - 192;
    const float4* pA = (const float4*)(Whh + (j      ) * H2_ + c0);
    const float4* pB = (const float4*)(Whh + (j +  64) * H2_ + c0);
    const float4* pC = (const float4*)(Whh + (j + 128) * H2_ + c0);
    const float4* pD = (const float4*)(Whh + (j + 192) * H2_ + c0);
    wA0=pA[0]; wA1=pA[1]; wA2=pA[2]; wA3=pA[3];
    wB0=pB[0]; wB1=pB[1]; wB2=pB[2]; wB3=pB[3];
    wC0=pC[0]; wC1=pC[1]; wC2=pC[2]; wC3=pC[3];
    wD0=pD[0]; wD1=pD[1]; wD2=pD[2]; wD3=pD[3];
  }

  const float bias_i = bih[j      ] + bhh[j      ];
  const float bias_f = bih[j +  64] + bhh[j +  64];
  const float bias_g = bih[j + 128] + bhh[j + 128];
  const float bias_o = bih[j + 192] + bhh[j + 192];
  float c_state = 0.0f;

  for (int i = tid; i < 2 * 1088; i += 1024) hxs[i] = 0.0f;
  __syncthreads();
  const int pb = tid / 96;                       // h1 stagers: tid < 384
  const int pj = tid - pb * 96;
  const int soff = 68 * ((2 * pj) >> 4) + 16 * pb + ((2 * pj) & 15);
  if (tid < 384) {
    *(float2*)&hxs[soff] =
        *(const float2*)&g_h1[((size_t)(b0 + pb) * T_ + 0) * 192 + pj * 2];
  }
  __syncthreads();

  const int ef = 17 * e;                         // f4 base of my k-chunk
  float4* scrw = scr4 + wv * 260 + jl * 65;
  const int we4 = e * 4;
  const int hoff = 68 * (12 + (j >> 4)) + 16 * e + (j & 15);  // e<4 only

  for (int s = 0; s < T_; ++s) {
    const int cur = s & 1, nxt = cur ^ 1;
    float2 pre = make_float2(0.0f, 0.0f);
    if (tid < 384 && s + 1 < T_) {
      pre = *(const float2*)&g_h1[((size_t)(b0 + pb) * T_ + (s + 1)) * 192 + pj * 2];
    }
    const float4* hb = (const float4*)(hxs + cur * 1088);
    float aI0=0.f,aI1=0.f,aI2=0.f,aI3=0.f;
    float aF0=0.f,aF1=0.f,aF2=0.f,aF3=0.f;
    float aG0=0.f,aG1=0.f,aG2=0.f,aG3=0.f;
    float aO0=0.f,aO1=0.f,aO2=0.f,aO3=0.f;
#define FB2(i) {                                                              \
    float4 v0 = hb[ef + 0 + i]; float4 v1 = hb[ef + 4 + i];                   \
    float4 v2 = hb[ef + 8 + i]; float4 v3 = hb[ef + 12 + i];                  \
    FMAROW(aI0, wA##i, v0) FMAROW(aF0, wB##i, v0)                             \
    FMAROW(aG0, wC##i, v0) FMAROW(aO0, wD##i, v0)                             \
    FMAROW(aI1, wA##i, v1) FMAROW(aF1, wB##i, v1)                             \
    FMAROW(aG1, wC##i, v1) FMAROW(aO1, wD##i, v1)                             \
    FMAROW(aI2, wA##i, v2) FMAROW(aF2, wB##i, v2)                             \
    FMAROW(aG2, wC##i, v2) FMAROW(aO2, wD##i, v2)                             \
    FMAROW(aI3, wA##i, v3) FMAROW(aF3, wB##i, v3)                             \
    FMAROW(aG3, wC##i, v3) FMAROW(aO3, wD##i, v3) }
    FB2(0) FB2(1) FB2(2) FB2(3)
#undef FB2
    scrw[we4 + 0] = make_float4(aI0, aF0, aG0, aO0);
    scrw[we4 + 1] = make_float4(aI1, aF1, aG1, aO1);
    scrw[we4 + 2] = make_float4(aI2, aF2, aG2, aO2);
    scrw[we4 + 3] = make_float4(aI3, aF3, aG3, aO3);
    if (e < 4) {                                 // cell (j, batch e)
      float gi = bias_i, gf = bias_f, gg = bias_g, go = bias_o;
#pragma unroll
      for (int ee = 0; ee < 16; ++ee) {
        float4 r = scrw[ee * 4 + e];
        gi += r.x; gf += r.y; gg += r.z; go += r.w;
      }
      float iv = fast_sigmoid(gi), fv = fast_sigmoid(gf), ov = fast_sigmoid(go);
      c_state = fv * c_state + iv * fast_tanh(gg);
      float h = ov * fast_tanh(c_state);
      hxs[nxt * 1088 + hoff] = h;
      if (s == T_ - 1) g_h2f[(b0 + e) * H2_ + j] = h;
    }
    if (tid < 384 && s + 1 < T_) *(float2*)&hxs[nxt * 1088 + soff] = pre;
    BAR_LGKM();
  }
}

// ---------------------------------------------------------------------------
// Tail: layer-2 backward (ONE step from zero state on h1[:,T-1,:]) + dense
// head. grid 128 x 256 threads, 8 batch/block. (negligible runtime)
// ---------------------------------------------------------------------------
__global__ __launch_bounds__(256)
void tail_kernel(const float* __restrict__ Wih, const float* __restrict__ bih,
                 const float* __restrict__ bhh,
                 const float* __restrict__ W1, const float* __restrict__ b1,
                 const float* __restrict__ W2, const float* __restrict__ b2,
                 float* __restrict__ out)
{
  const int tid = threadIdx.x;
  const int b0  = blockIdx.x * 8;

  __shared__ __align__(16) float hl[8][192];    // h1 at t = T-1
  __shared__ float gb[G2_ * 9];
  __shared__ __align__(16) float last[8][128];  // [h2f | h2b]
  __shared__ float db[8][32];

  for (int i = tid; i < 8 * 96; i += 256) {
    int bb = i / 96, jj = i - (i / 96) * 96;
    *(float2*)&hl[bb][jj * 2] =
        *(const float2*)&g_h1[((size_t)(b0 + bb) * T_ + (T_ - 1)) * 192 + jj * 2];
  }
  for (int i = tid; i < 8 * 64; i += 256) {
    int bb = i >> 6, jj = i & 63;
    last[bb][jj] = g_h2f[(b0 + bb) * H2_ + jj];
  }
  __syncthreads();

  {
    const int gg_ = tid;
    const float* wr = Wih + gg_ * 192;
    const float bias = bih[gg_] + bhh[gg_];
    float acc[8];
#pragma unroll
    for (int b = 0; b < 8; ++b) acc[b] = bias;
#pragma unroll 4
    for (int qq = 0; qq < 48; ++qq) {
      float4 wv = *(const float4*)&wr[qq * 4];
#pragma unroll
      for (int b = 0; b < 8; ++b) {
        float4 v = *(const float4*)&hl[b][qq * 4];
        acc[b] = fmaf(wv.x, v.x, acc[b]);
        acc[b] = fmaf(wv.y, v.y, acc[b]);
        acc[b] = fmaf(wv.z, v.z, acc[b]);
        acc[b] = fmaf(wv.w, v.w, acc[b]);
      }
    }
#pragma unroll
    for (int b = 0; b < 8; ++b) gb[gg_ * 9 + b] = acc[b];
  }
  __syncthreads();

  for (int p = tid; p < 512; p += 256) {
    int jj = p & 63, bb = p >> 6;
    float gi = gb[(jj      ) * 9 + bb];
    float gg = gb[(jj + 128) * 9 + bb];
    float go = gb[(jj + 192) * 9 + bb];
    float c  = fast_sigmoid(gi) * fast_tanh(gg);
    float h  = fast_sigmoid(go) * fast_tanh(c);
    last[bb][64 + jj] = h;
  }
  __syncthreads();

  {
    int u = tid & 31, bb = tid >> 5;
    const float* wr1 = W1 + u * 128;
    float a = b1[u];
#pragma unroll
    for (int qq = 0; qq < 32; ++qq) {
      float4 wv = *(const float4*)&wr1[qq * 4];
      float4 v  = *(const float4*)&last[bb][qq * 4];
      a = fmaf(wv.x, v.x, a); a = fmaf(wv.y, v.y, a);
      a = fmaf(wv.z, v.z, a); a = fmaf(wv.w, v.w, a);
    }
    db[bb][u] = fmaxf(a, 0.0f);
  }
  __syncthreads();

  if (tid < 8) {
    float a = b2[0];
#pragma unroll
    for (int u2 = 0; u2 < 32; ++u2) a = fmaf(db[tid][u2], W2[u2], a);
    out[b0 + tid] = a;
  }
}

extern "C" void kernel_launch(void* const* d_in, const int* in_sizes, int n_in,
                              void* d_out, int out_size, void* d_ws, size_t ws_size,
                              hipStream_t stream)
{
  const float* x     = (const float*)d_in[0];
  const float* Wih1f = (const float*)d_in[1];
  const float* Whh1f = (const float*)d_in[2];
  const float* bih1f = (const float*)d_in[3];
  const float* bhh1f = (const float*)d_in[4];
  const float* Wih1b = (const float*)d_in[5];
  const float* Whh1b = (const float*)d_in[6];
  const float* bih1b = (const float*)d_in[7];
  const float* bhh1b = (const float*)d_in[8];
  const float* Wih2f = (const float*)d_in[9];
  const float* Whh2f = (const float*)d_in[10];
  const float* bih2f = (const float*)d_in[11];
  const float* bhh2f = (const float*)d_in[12];
  const float* Wih2b = (const float*)d_in[13];
  /* Whh2b (d_in[14]) unused: layer-2 backward at t=T-1 is one step from h=0 */
  const float* bih2b = (const float*)d_in[15];
  const float* bhh2b = (const float*)d_in[16];
  const float* W1    = (const float*)d_in[17];
  const float* b1    = (const float*)d_in[18];
  const float* W2    = (const float*)d_in[19];
  const float* b2    = (const float*)d_in[20];

  (void)d_ws; (void)ws_size; (void)in_sizes; (void)n_in; (void)out_size;

  lstm1_kernel<<<dim3(128, 2), 768, 0, stream>>>(
      x, Wih1f, Whh1f, bih1f, bhh1f, Wih1b, Whh1b, bih1b, bhh1b);
  lstm2f_kernel<<<256, 1024, 0, stream>>>(
      Wih2f, Whh2f, bih2f, bhh2f);
  tail_kernel<<<128, 256, 0, stream>>>(
      Wih2b, bih2b, bhh2b, W1, b1, W2, b2, (float*)d_out);
}

// Round 5
// 2996.295 us; speedup vs baseline: 1.2682x; 1.2682x over previous
//
#include <hip/hip_runtime.h>
#include <math.h>

#define B_  1024
#define T_  512
#define D_  30
#define H1_ 96
#define G1_ 384
#define H2_ 64
#define G2_ 256

// Inter-kernel buffers as device globals (.bss, bound at module load).
__device__ float g_h1[(size_t)B_ * T_ * 192];   // 384 MiB: layer-1 output
__device__ float g_h2f[(size_t)B_ * H2_];       // layer-2 fwd final state

__device__ __forceinline__ float fast_tanh(float v) {
  float a = fabsf(v);
  float e = __expf(-2.0f * a);
  float t = 1.0f - 2.0f * e / (1.0f + e);
  return v < 0.0f ? -t : t;
}
__device__ __forceinline__ float fast_sigmoid(float v) {
  return 0.5f + 0.5f * fast_tanh(0.5f * v);   // exact identity, overflow-safe
}

#define FMAROW(a_, w_, v_)                                                    \
  a_ = fmaf(w_.x, v_.x, a_); a_ = fmaf(w_.y, v_.y, a_);                       \
  a_ = fmaf(w_.z, v_.z, a_); a_ = fmaf(w_.w, v_.w, a_);

// Barrier with LDS-only drain (skips vmcnt: g_h1 stores + x prefetch stay
// in flight across steps).
#define BAR_LGKM() do {                                                       \
    asm volatile("s_waitcnt lgkmcnt(0)" ::: "memory");                        \
    __builtin_amdgcn_s_barrier();                                             \
    asm volatile("" ::: "memory");                                            \
  } while (0)

// ---------------------------------------------------------------------------
// Layer 1: bidirectional LSTM over x (B,T,30) -> g_h1 (B,T,192)
// grid (128, 2). 768 threads, tid = j*8 + e (j = unit 0..95 owning gate rows
// j,j+96,j+192,j+288; e = k-chunk 0..7 of 16 k). All 8 chunk-partials of a
// unit live in ONE wave -> reduction is wave-internal (LDS scratch +
// compiler lgkmcnt, NO barrier); ONE block barrier per step.
// SCRATCH BANKS (R4 bug fixed): layout offset_f4(jl,i,e') = jl*73 + i*9 + e'.
//   write (fixed i, lanes jl,e): quad=(jl+i+e)%8  -> 2 lanes/quad: free
//   read  (fixed k, lanes jl,e): quad=(jl+e+k)%8  -> 2 lanes/quad: free
// (R4 had jl*65,e*8 in f4 units = 4,0 mod 32 floats -> 8-way, 8.2e8 cycles.)
// v[128]: chunks 0-1 = x_t (30 + 2 zero-pad), chunks 2-7 = h_{t-1}.
// ---------------------------------------------------------------------------
__global__ __launch_bounds__(768, 4)
void lstm1_kernel(const float* __restrict__ x,
                  const float* __restrict__ Wih_f, const float* __restrict__ Whh_f,
                  const float* __restrict__ bih_f, const float* __restrict__ bhh_f,
                  const float* __restrict__ Wih_b, const float* __restrict__ Whh_b,
                  const float* __restrict__ bih_b, const float* __restrict__ bhh_b)
{
  const int tid = threadIdx.x;
  const int dir = blockIdx.y;
  const int b0  = blockIdx.x * 8;

  const float* __restrict__ Wih = dir ? Wih_b : Wih_f;
  const float* __restrict__ Whh = dir ? Whh_b : Whh_f;
  const float* __restrict__ bih = dir ? bih_b : bih_f;
  const float* __restrict__ bhh = dir ? bhh_b : bhh_f;

  const int j  = tid >> 3;                       // unit 0..95
  const int e  = tid & 7;                        // k-chunk 0..7
  const int wv = tid >> 6;                       // wave 0..11
  const int jl = j & 7;                          // unit-in-wave 0..7

  // hx: [2 buf][8 chunks][8 b * 16 + 4 pad = 132]  (8.4 KB)
  __shared__ __align__(16) float hxs[2 * 1056];
  // scratch: per-wave [8 jl][8 i(batch)][8 e'] f4, strides 73/9/1 (bank-clean)
  __shared__ float4 scr4[12 * 584];              // 112.1 KB

  // 16 NAMED float4 regs: 4 gate rows x 4 float4 over k in [16e, 16e+16).
  float4 wA0,wA1,wA2,wA3, wB0,wB1,wB2,wB3, wC0,wC1,wC2,wC3, wD0,wD1,wD2,wD3;
  if (e < 2) {                                   // k = 0..31: x-part (30 + 2 pad)
    const int k0 = e * 16;
#define LDXF(r_, kk) (((kk) < D_) ? Wih[(r_) * D_ + (kk)] : 0.0f)
#define LW4(d0,d1,d2,d3, r_) {                                                \
    d0 = make_float4(LDXF(r_,k0+ 0),LDXF(r_,k0+ 1),LDXF(r_,k0+ 2),LDXF(r_,k0+ 3)); \
    d1 = make_float4(LDXF(r_,k0+ 4),LDXF(r_,k0+ 5),LDXF(r_,k0+ 6),LDXF(r_,k0+ 7)); \
    d2 = make_float4(LDXF(r_,k0+ 8),LDXF(r_,k0+ 9),LDXF(r_,k0+10),LDXF(r_,k0+11)); \
    d3 = make_float4(LDXF(r_,k0+12),LDXF(r_,k0+13),LDXF(r_,k0+14),LDXF(r_,k0+15)); }
    LW4(wA0,wA1,wA2,wA3, j      )
    LW4(wB0,wB1,wB2,wB3, j +  96)
    LW4(wC0,wC1,wC2,wC3, j + 192)
    LW4(wD0,wD1,wD2,wD3, j + 288)
#undef LW4
#undef LDXF
  } else {                                       // k = 16e..16e+15: h-part
    const int c0 = e * 16 - 32;
    const float4* pA = (const float4*)(Whh + (j      ) * H1_ + c0);
    const float4* pB = (const float4*)(Whh + (j +  96) * H1_ + c0);
    const float4* pC = (const float4*)(Whh + (j + 192) * H1_ + c0);
    const float4* pD = (const float4*)(Whh + (j + 288) * H1_ + c0);
    wA0=pA[0]; wA1=pA[1]; wA2=pA[2]; wA3=pA[3];
    wB0=pB[0]; wB1=pB[1]; wB2=pB[2]; wB3=pB[3];
    wC0=pC[0]; wC1=pC[1]; wC2=pC[2]; wC3=pC[3];
    wD0=pD[0]; wD1=pD[1]; wD2=pD[2]; wD3=pD[3];
  }

  const float bias_i = bih[j      ] + bhh[j      ];
  const float bias_f = bih[j +  96] + bhh[j +  96];
  const float bias_g = bih[j + 192] + bhh[j + 192];
  const float bias_o = bih[j + 288] + bhh[j + 288];
  float c_state = 0.0f;

  for (int i = tid; i < 2 * 1056; i += 768) hxs[i] = 0.0f;
  __syncthreads();
  const int xb = tid / 30;                       // x stagers: tid < 240
  const int xd = tid - xb * 30;
  const int xoff = 132 * (xd >> 4) + 16 * xb + (xd & 15);
  if (tid < 240) {
    const int t0 = dir ? (T_ - 1) : 0;
    hxs[xoff] = x[((size_t)(b0 + xb) * T_ + t0) * D_ + xd];
  }
  __syncthreads();

  const int ef = 33 * e;                         // f4 base of my k-chunk
  float4* swp = scr4 + wv * 584 + jl * 73 + e;       // writer base: [i*9]
  const float4* srd = scr4 + wv * 584 + jl * 73 + e * 9;  // reader: [k]
  const int hoff = 132 * (2 + (j >> 4)) + 16 * e + ((32 + j) & 15);
  float* __restrict__ gp = g_h1 + ((size_t)(b0 + e) * T_) * 192
                                + (size_t)dir * 96 + j;

  for (int s = 0; s < T_; ++s) {
    const int t   = dir ? (T_ - 1 - s) : s;
    const int cur = s & 1, nxt = cur ^ 1;
    float xn = 0.0f;
    if (tid < 240 && s + 1 < T_) {
      const int tn = dir ? (t - 1) : (t + 1);
      xn = x[((size_t)(b0 + xb) * T_ + tn) * D_ + xd];
    }
    const float4* hb = (const float4*)(hxs + cur * 1056);
    float aI0=0.f,aI1=0.f,aI2=0.f,aI3=0.f,aI4=0.f,aI5=0.f,aI6=0.f,aI7=0.f;
    float aF0=0.f,aF1=0.f,aF2=0.f,aF3=0.f,aF4=0.f,aF5=0.f,aF6=0.f,aF7=0.f;
    float aG0=0.f,aG1=0.f,aG2=0.f,aG3=0.f,aG4=0.f,aG5=0.f,aG6=0.f,aG7=0.f;
    float aO0=0.f,aO1=0.f,aO2=0.f,aO3=0.f,aO4=0.f,aO5=0.f,aO6=0.f,aO7=0.f;
#define FB1(i) {                                                              \
    float4 v0 = hb[ef +  0 + i]; float4 v1 = hb[ef +  4 + i];                 \
    float4 v2 = hb[ef +  8 + i]; float4 v3 = hb[ef + 12 + i];                 \
    float4 v4 = hb[ef + 16 + i]; float4 v5 = hb[ef + 20 + i];                 \
    float4 v6 = hb[ef + 24 + i]; float4 v7 = hb[ef + 28 + i];                 \
    FMAROW(aI0, wA##i, v0) FMAROW(aF0, wB##i, v0)                             \
    FMAROW(aG0, wC##i, v0) FMAROW(aO0, wD##i, v0)                             \
    FMAROW(aI1, wA##i, v1) FMAROW(aF1, wB##i, v1)                             \
    FMAROW(aG1, wC##i, v1) FMAROW(aO1, wD##i, v1)                             \
    FMAROW(aI2, wA##i, v2) FMAROW(aF2, wB##i, v2)                             \
    FMAROW(aG2, wC##i, v2) FMAROW(aO2, wD##i, v2)                             \
    FMAROW(aI3, wA##i, v3) FMAROW(aF3, wB##i, v3)                             \
    FMAROW(aG3, wC##i, v3) FMAROW(aO3, wD##i, v3)                             \
    FMAROW(aI4, wA##i, v4) FMAROW(aF4, wB##i, v4)                             \
    FMAROW(aG4, wC##i, v4) FMAROW(aO4, wD##i, v4)                             \
    FMAROW(aI5, wA##i, v5) FMAROW(aF5, wB##i, v5)                             \
    FMAROW(aG5, wC##i, v5) FMAROW(aO5, wD##i, v5)                             \
    FMAROW(aI6, wA##i, v6) FMAROW(aF6, wB##i, v6)                             \
    FMAROW(aG6, wC##i, v6) FMAROW(aO6, wD##i, v6)                             \
    FMAROW(aI7, wA##i, v7) FMAROW(aF7, wB##i, v7)                             \
    FMAROW(aG7, wC##i, v7) FMAROW(aO7, wD##i, v7) }
    FB1(0) FB1(1) FB1(2) FB1(3)
#undef FB1
    // wave-internal reduction: write my 8 batch-partials ([i*9]), read my
    // batch's 8 chunk-partials ([k]). Same wave -> no barrier needed.
    swp[0*9] = make_float4(aI0, aF0, aG0, aO0);
    swp[1*9] = make_float4(aI1, aF1, aG1, aO1);
    swp[2*9] = make_float4(aI2, aF2, aG2, aO2);
    swp[3*9] = make_float4(aI3, aF3, aG3, aO3);
    swp[4*9] = make_float4(aI4, aF4, aG4, aO4);
    swp[5*9] = make_float4(aI5, aF5, aG5, aO5);
    swp[6*9] = make_float4(aI6, aF6, aG6, aO6);
    swp[7*9] = make_float4(aI7, aF7, aG7, aO7);
    {
      float4 r0 = srd[0], r1 = srd[1], r2 = srd[2], r3 = srd[3];
      float4 r4 = srd[4], r5 = srd[5], r6 = srd[6], r7 = srd[7];
      float gi = bias_i + r0.x + r1.x + r2.x + r3.x + r4.x + r5.x + r6.x + r7.x;
      float gf = bias_f + r0.y + r1.y + r2.y + r3.y + r4.y + r5.y + r6.y + r7.y;
      float gg = bias_g + r0.z + r1.z + r2.z + r3.z + r4.z + r5.z + r6.z + r7.z;
      float go = bias_o + r0.w + r1.w + r2.w + r3.w + r4.w + r5.w + r6.w + r7.w;
      float iv = fast_sigmoid(gi);
      float fv = fast_sigmoid(gf);
      float ov = fast_sigmoid(go);
      c_state = fv * c_state + iv * fast_tanh(gg);
      float h = ov * fast_tanh(c_state);
      hxs[nxt * 1056 + hoff] = h;                // my cell = (unit j, batch e)
      gp[(size_t)t * 192] = h;
    }
    if (tid < 240 && s + 1 < T_) hxs[nxt * 1056 + xoff] = xn;
    BAR_LGKM();
  }
}

// ---------------------------------------------------------------------------
// Layer 2 forward scan: g_h1 (B,T,192) -> g_h2f (B,64).
// grid 256: 4 batch/block. 1024 threads, tid = j*16 + e (j = unit 0..63,
// e = k-chunk 0..15). Wave-internal reduction; lanes e<4 update cell
// (j, batch e). Scratch layout offset_f4(jl,i,e') = jl*70 + i*17 + e':
//   write quad=(6jl+i+e)%8 -> 2/quad free; read quad=(6jl+e+k)%8 -> 2/quad.
// chunks 0-11 = h1_t, 12-15 = h2_{t-1}. One barrier/step.
// ---------------------------------------------------------------------------
__global__ __launch_bounds__(1024, 4)
void lstm2f_kernel(const float* __restrict__ Wih, const float* __restrict__ Whh,
                   const float* __restrict__ bih, const float* __restrict__ bhh)
{
  const int tid = threadIdx.x;
  const int b0  = blockIdx.x * 4;
  const int j   = tid >> 4;                      // unit 0..63
  const int e   = tid & 15;                      // k-chunk 0..15
  const int wv  = tid >> 6;                      // wave 0..15
  const int jl  = j & 3;                         // unit-in-wave 0..3

  __shared__ __align__(16) float hxs[2 * 1088];  // [2][16 c][68]  (8.7 KB)
  __shared__ float4 scr4[16 * 280];              // per-wave [4][4][16]+pad, 71.7 KB

  const int k0 = e * 16;
  float4 wA0,wA1,wA2,wA3, wB0,wB1,wB2,wB3, wC0,wC1,wC2,wC3, wD0,wD1,wD2,wD3;
  if (e < 12) {
    const float4* pA = (const float4*)(Wih + (j      ) * 192 + k0);
    const float4* pB = (const float4*)(Wih + (j +  64) * 192 + k0);
    const float4* pC = (const float4*)(Wih + (j + 128) * 192 + k0);
    const float4* pD = (const float4*)(Wih + (j + 192) * 192 + k0);
    wA0=pA[0]; wA1=pA[1]; wA2=pA[2]; wA3=pA[3];
    wB0=pB[0]; wB1=pB[1]; wB2=pB[2]; wB3=pB[3];
    wC0=pC[0]; wC1=pC[1]; wC2=pC[2]; wC3=pC[3];
    wD0=pD[0]; wD1=pD[1]; wD2=pD[2]; wD3=pD[3];
  } else {
    const int c0 = k0 - 192;
    const float4* pA = (const float4*)(Whh + (j      ) * H2_ + c0);
    const float4* pB = (const float4*)(Whh + (j +  64) * H2_ + c0);
    const float4* pC = (const float4*)(Whh + (j + 128) * H2_ + c0);
    const float4* pD = (const float4*)(Whh + (j + 192) * H2_ + c0);
    wA0=pA[0]; wA1=pA[1]; wA2=pA[2]; wA3=pA[3];
    wB0=pB[0]; wB1=pB[1]; wB2=pB[2]; wB3=pB[3];
    wC0=pC[0]; wC1=pC[1]; wC2=pC[2]; wC3=pC[3];
    wD0=pD[0]; wD1=pD[1]; wD2=pD[2]; wD3=pD[3];
  }

  const float bias_i = bih[j      ] + bhh[j      ];
  const float bias_f = bih[j +  64] + bhh[j +  64];
  const float bias_g = bih[j + 128] + bhh[j + 128];
  const float bias_o = bih[j + 192] + bhh[j + 192];
  float c_state = 0.0f;

  for (int i = tid; i < 2 * 1088; i += 1024) hxs[i] = 0.0f;
  __syncthreads();
  const int pb = tid / 96;                       // h1 stagers: tid < 384
  const int pj = tid - pb * 96;
  const int soff = 68 * ((2 * pj) >> 4) + 16 * pb + ((2 * pj) & 15);
  if (tid < 384) {
    *(float2*)&hxs[soff] =
        *(const float2*)&g_h1[((size_t)(b0 + pb) * T_ + 0) * 192 + pj * 2];
  }
  __syncthreads();

  const int ef = 17 * e;                         // f4 base of my k-chunk
  float4* swp = scr4 + wv * 280 + jl * 70 + e;        // writer base: [i*17]
  const float4* srd = scr4 + wv * 280 + jl * 70 + e * 17;  // reader (e<4): [k]
  const int hoff = 68 * (12 + (j >> 4)) + 16 * e + (j & 15);  // e<4 only

  for (int s = 0; s < T_; ++s) {
    const int cur = s & 1, nxt = cur ^ 1;
    float2 pre = make_float2(0.0f, 0.0f);
    if (tid < 384 && s + 1 < T_) {
      pre = *(const float2*)&g_h1[((size_t)(b0 + pb) * T_ + (s + 1)) * 192 + pj * 2];
    }
    const float4* hb = (const float4*)(hxs + cur * 1088);
    float aI0=0.f,aI1=0.f,aI2=0.f,aI3=0.f;
    float aF0=0.f,aF1=0.f,aF2=0.f,aF3=0.f;
    float aG0=0.f,aG1=0.f,aG2=0.f,aG3=0.f;
    float aO0=0.f,aO1=0.f,aO2=0.f,aO3=0.f;
#define FB2(i) {                                                              \
    float4 v0 = hb[ef + 0 + i]; float4 v1 = hb[ef + 4 + i];                   \
    float4 v2 = hb[ef + 8 + i]; float4 v3 = hb[ef + 12 + i];                  \
    FMAROW(aI0, wA##i, v0) FMAROW(aF0, wB##i, v0)                             \
    FMAROW(aG0, wC##i, v0) FMAROW(aO0, wD##i, v0)                             \
    FMAROW(aI1, wA##i, v1) FMAROW(aF1, wB##i, v1)                             \
    FMAROW(aG1, wC##i, v1) FMAROW(aO1, wD##i, v1)                             \
    FMAROW(aI2, wA##i, v2) FMAROW(aF2, wB##i, v2)                             \
    FMAROW(aG2, wC##i, v2) FMAROW(aO2, wD##i, v2)                             \
    FMAROW(aI3, wA##i, v3) FMAROW(aF3, wB##i, v3)                             \
    FMAROW(aG3, wC##i, v3) FMAROW(aO3, wD##i, v3) }
    FB2(0) FB2(1) FB2(2) FB2(3)
#undef FB2
    swp[0*17] = make_float4(aI0, aF0, aG0, aO0);
    swp[1*17] = make_float4(aI1, aF1, aG1, aO1);
    swp[2*17] = make_float4(aI2, aF2, aG2, aO2);
    swp[3*17] = make_float4(aI3, aF3, aG3, aO3);
    if (e < 4) {                                 // cell (j, batch e)
      float gi = bias_i, gf = bias_f, gg = bias_g, go = bias_o;
#pragma unroll
      for (int k = 0; k < 16; ++k) {
        float4 r = srd[k];
        gi += r.x; gf += r.y; gg += r.z; go += r.w;
      }
      float iv = fast_sigmoid(gi), fv = fast_sigmoid(gf), ov = fast_sigmoid(go);
      c_state = fv * c_state + iv * fast_tanh(gg);
      float h = ov * fast_tanh(c_state);
      hxs[nxt * 1088 + hoff] = h;
      if (s == T_ - 1) g_h2f[(b0 + e) * H2_ + j] = h;
    }
    if (tid < 384 && s + 1 < T_) *(float2*)&hxs[nxt * 1088 + soff] = pre;
    BAR_LGKM();
  }
}

// ---------------------------------------------------------------------------
// Tail: layer-2 backward (ONE step from zero state on h1[:,T-1,:]) + dense
// head. grid 128 x 256 threads, 8 batch/block. (negligible runtime)
// ---------------------------------------------------------------------------
__global__ __launch_bounds__(256)
void tail_kernel(const float* __restrict__ Wih, const float* __restrict__ bih,
                 const float* __restrict__ bhh,
                 const float* __restrict__ W1, const float* __restrict__ b1,
                 const float* __restrict__ W2, const float* __restrict__ b2,
                 float* __restrict__ out)
{
  const int tid = threadIdx.x;
  const int b0  = blockIdx.x * 8;

  __shared__ __align__(16) float hl[8][192];    // h1 at t = T-1
  __shared__ float gb[G2_ * 9];
  __shared__ __align__(16) float last[8][128];  // [h2f | h2b]
  __shared__ float db[8][32];

  for (int i = tid; i < 8 * 96; i += 256) {
    int bb = i / 96, jj = i - (i / 96) * 96;
    *(float2*)&hl[bb][jj * 2] =
        *(const float2*)&g_h1[((size_t)(b0 + bb) * T_ + (T_ - 1)) * 192 + jj * 2];
  }
  for (int i = tid; i < 8 * 64; i += 256) {
    int bb = i >> 6, jj = i & 63;
    last[bb][jj] = g_h2f[(b0 + bb) * H2_ + jj];
  }
  __syncthreads();

  {
    const int gg_ = tid;
    const float* wr = Wih + gg_ * 192;
    const float bias = bih[gg_] + bhh[gg_];
    float acc[8];
#pragma unroll
    for (int b = 0; b < 8; ++b) acc[b] = bias;
#pragma unroll 4
    for (int qq = 0; qq < 48; ++qq) {
      float4 wv = *(const float4*)&wr[qq * 4];
#pragma unroll
      for (int b = 0; b < 8; ++b) {
        float4 v = *(const float4*)&hl[b][qq * 4];
        acc[b] = fmaf(wv.x, v.x, acc[b]);
        acc[b] = fmaf(wv.y, v.y, acc[b]);
        acc[b] = fmaf(wv.z, v.z, acc[b]);
        acc[b] = fmaf(wv.w, v.w, acc[b]);
      }
    }
#pragma unroll
    for (int b = 0; b < 8; ++b) gb[gg_ * 9 + b] = acc[b];
  }
  __syncthreads();

  for (int p = tid; p < 512; p += 256) {
    int jj = p & 63, bb = p >> 6;
    float gi = gb[(jj      ) * 9 + bb];
    float gg = gb[(jj + 128) * 9 + bb];
    float go = gb[(jj + 192) * 9 + bb];
    float c  = fast_sigmoid(gi) * fast_tanh(gg);
    float h  = fast_sigmoid(go) * fast_tanh(c);
    last[bb][64 + jj] = h;
  }
  __syncthreads();

  {
    int u = tid & 31, bb = tid >> 5;
    const float* wr1 = W1 + u * 128;
    float a = b1[u];
#pragma unroll
    for (int qq = 0; qq < 32; ++qq) {
      float4 wv = *(const float4*)&wr1[qq * 4];
      float4 v  = *(const float4*)&last[bb][qq * 4];
      a = fmaf(wv.x, v.x, a); a = fmaf(wv.y, v.y, a);
      a = fmaf(wv.z, v.z, a); a = fmaf(wv.w, v.w, a);
    }
    db[bb][u] = fmaxf(a, 0.0f);
  }
  __syncthreads();

  if (tid < 8) {
    float a = b2[0];
#pragma unroll
    for (int u2 = 0; u2 < 32; ++u2) a = fmaf(db[tid][u2], W2[u2], a);
    out[b0 + tid] = a;
  }
}

extern "C" void kernel_launch(void* const* d_in, const int* in_sizes, int n_in,
                              void* d_out, int out_size, void* d_ws, size_t ws_size,
                              hipStream_t stream)
{
  const float* x     = (const float*)d_in[0];
  const float* Wih1f = (const float*)d_in[1];
  const float* Whh1f = (const float*)d_in[2];
  const float* bih1f = (const float*)d_in[3];
  const float* bhh1f = (const float*)d_in[4];
  const float* Wih1b = (const float*)d_in[5];
  const float* Whh1b = (const float*)d_in[6];
  const float* bih1b = (const float*)d_in[7];
  const float* bhh1b = (const float*)d_in[8];
  const float* Wih2f = (const float*)d_in[9];
  const float* Whh2f = (const float*)d_in[10];
  const float* bih2f = (const float*)d_in[11];
  const float* bhh2f = (const float*)d_in[12];
  const float* Wih2b = (const float*)d_in[13];
  /* Whh2b (d_in[14]) unused: layer-2 backward at t=T-1 is one step from h=0 */
  const float* bih2b = (const float*)d_in[15];
  const float* bhh2b = (const float*)d_in[16];
  const float* W1    = (const float*)d_in[17];
  const float* b1    = (const float*)d_in[18];
  const float* W2    = (const float*)d_in[19];
  const float* b2    = (const float*)d_in[20];

  (void)d_ws; (void)ws_size; (void)in_sizes; (void)n_in; (void)out_size;

  lstm1_kernel<<<dim3(128, 2), 768, 0, stream>>>(
      x, Wih1f, Whh1f, bih1f, bhh1f, Wih1b, Whh1b, bih1b, bhh1b);
  lstm2f_kernel<<<256, 1024, 0, stream>>>(
      Wih2f, Whh2f, bih2f, bhh2f);
  tail_kernel<<<128, 256, 0, stream>>>(
      Wih2b, bih2b, bhh2b, W1, b1, W2, b2, (float*)d_out);
}

// Round 6
// 2755.641 us; speedup vs baseline: 1.3789x; 1.0873x over previous
//
#include <hip/hip_runtime.h>
#include <math.h>

#define B_  1024
#define T_  512
#define D_  30
#define H1_ 96
#define G1_ 384
#define H2_ 64
#define G2_ 256

// Inter-kernel buffers as device globals (.bss, bound at module load).
__device__ float g_h1[(size_t)B_ * T_ * 192];   // 384 MiB: layer-1 output
__device__ float g_h2f[(size_t)B_ * H2_];       // layer-2 fwd final state

__device__ __forceinline__ float fast_tanh(float v) {
  float a = fabsf(v);
  float e = __expf(-2.0f * a);
  float t = 1.0f - 2.0f * e / (1.0f + e);
  return v < 0.0f ? -t : t;
}
__device__ __forceinline__ float fast_sigmoid(float v) {
  return 0.5f + 0.5f * fast_tanh(0.5f * v);   // exact identity, overflow-safe
}

#define FMAROW(a_, w_, v_)                                                    \
  a_ = fmaf(w_.x, v_.x, a_); a_ = fmaf(w_.y, v_.y, a_);                       \
  a_ = fmaf(w_.z, v_.z, a_); a_ = fmaf(w_.w, v_.w, a_);

// Barrier with LDS-only drain (skips vmcnt: global stores + prefetches stay
// in flight across steps; their consumers get compiler-inserted vmcnt waits).
#define BAR_LGKM() do {                                                       \
    asm volatile("s_waitcnt lgkmcnt(0)" ::: "memory");                        \
    __builtin_amdgcn_s_barrier();                                             \
    asm volatile("" ::: "memory");                                            \
  } while (0)

// ---------------------------------------------------------------------------
// Layer 1: bidirectional LSTM over x (B,T,30) -> g_h1 (B,T,192)
// grid (128, 2). 768 threads, tid = j*8 + e (j = unit 0..95 owning gate rows
// j,j+96,j+192,j+288; e = k-chunk 0..7 of 16 k). All 8 chunk-partials of a
// unit live in ONE wave -> reduction is wave-internal (LDS scratch, NO
// barrier); ONE block barrier per step. Every lane is a cell-updater
// (96 units x 8 batches = 768) -> no masked-issue waste.
// SCRATCH (R5 fix): scalar b32, off = g*584 + jl*72 + i*9 + e (floats).
//   584=8, 72=8 mod 32; 9 odd. write banks (8g+8jl+9i+e): lanes (jl,e) ->
//   2/bank free. read banks (8g+8jl+9e+k): 9e distinct mod 32 -> 2/bank free.
//   (R5's float4 quad layout measured 1.1e8 conflict cycles; scalar-odd-
//   stride is the only pattern that has measured clean: 0.9e6.)
// v[128]: chunks 0-1 = x_t (30 + 2 zero-pad), chunks 2-7 = h_{t-1}.
// ---------------------------------------------------------------------------
__global__ __launch_bounds__(768, 4)
void lstm1_kernel(const float* __restrict__ x,
                  const float* __restrict__ Wih_f, const float* __restrict__ Whh_f,
                  const float* __restrict__ bih_f, const float* __restrict__ bhh_f,
                  const float* __restrict__ Wih_b, const float* __restrict__ Whh_b,
                  const float* __restrict__ bih_b, const float* __restrict__ bhh_b)
{
  const int tid = threadIdx.x;
  const int dir = blockIdx.y;
  const int b0  = blockIdx.x * 8;

  const float* __restrict__ Wih = dir ? Wih_b : Wih_f;
  const float* __restrict__ Whh = dir ? Whh_b : Whh_f;
  const float* __restrict__ bih = dir ? bih_b : bih_f;
  const float* __restrict__ bhh = dir ? bhh_b : bhh_f;

  const int j  = tid >> 3;                       // unit 0..95
  const int e  = tid & 7;                        // k-chunk 0..7
  const int wv = tid >> 6;                       // wave 0..11
  const int jl = j & 7;                          // unit-in-wave 0..7

  // hx: [2 buf][8 chunks][8 b * 16 + 4 pad = 132]  (8.4 KB)
  __shared__ __align__(16) float hxs[2 * 1056];
  // scratch: per-wave scalar floats [4 g:584][8 jl:72][8 i:9][8 e:1]
  __shared__ float scr[12 * 2336];               // 112.1 KB

  // 16 NAMED float4 regs: 4 gate rows x 4 float4 over k in [16e, 16e+16).
  float4 wA0,wA1,wA2,wA3, wB0,wB1,wB2,wB3, wC0,wC1,wC2,wC3, wD0,wD1,wD2,wD3;
  if (e < 2) {                                   // k = 0..31: x-part (30 + 2 pad)
    const int k0 = e * 16;
#define LDXF(r_, kk) (((kk) < D_) ? Wih[(r_) * D_ + (kk)] : 0.0f)
#define LW4(d0,d1,d2,d3, r_) {                                                \
    d0 = make_float4(LDXF(r_,k0+ 0),LDXF(r_,k0+ 1),LDXF(r_,k0+ 2),LDXF(r_,k0+ 3)); \
    d1 = make_float4(LDXF(r_,k0+ 4),LDXF(r_,k0+ 5),LDXF(r_,k0+ 6),LDXF(r_,k0+ 7)); \
    d2 = make_float4(LDXF(r_,k0+ 8),LDXF(r_,k0+ 9),LDXF(r_,k0+10),LDXF(r_,k0+11)); \
    d3 = make_float4(LDXF(r_,k0+12),LDXF(r_,k0+13),LDXF(r_,k0+14),LDXF(r_,k0+15)); }
    LW4(wA0,wA1,wA2,wA3, j      )
    LW4(wB0,wB1,wB2,wB3, j +  96)
    LW4(wC0,wC1,wC2,wC3, j + 192)
    LW4(wD0,wD1,wD2,wD3, j + 288)
#undef LW4
#undef LDXF
  } else {                                       // k = 16e..16e+15: h-part
    const int c0 = e * 16 - 32;
    const float4* pA = (const float4*)(Whh + (j      ) * H1_ + c0);
    const float4* pB = (const float4*)(Whh + (j +  96) * H1_ + c0);
    const float4* pC = (const float4*)(Whh + (j + 192) * H1_ + c0);
    const float4* pD = (const float4*)(Whh + (j + 288) * H1_ + c0);
    wA0=pA[0]; wA1=pA[1]; wA2=pA[2]; wA3=pA[3];
    wB0=pB[0]; wB1=pB[1]; wB2=pB[2]; wB3=pB[3];
    wC0=pC[0]; wC1=pC[1]; wC2=pC[2]; wC3=pC[3];
    wD0=pD[0]; wD1=pD[1]; wD2=pD[2]; wD3=pD[3];
  }

  const float bias_i = bih[j      ] + bhh[j      ];
  const float bias_f = bih[j +  96] + bhh[j +  96];
  const float bias_g = bih[j + 192] + bhh[j + 192];
  const float bias_o = bih[j + 288] + bhh[j + 288];
  float c_state = 0.0f;

  for (int i = tid; i < 2 * 1056; i += 768) hxs[i] = 0.0f;
  __syncthreads();
  const int xb = tid / 30;                       // x stagers: tid < 240
  const int xd = tid - xb * 30;
  const int xoff = 132 * (xd >> 4) + 16 * xb + (xd & 15);
  if (tid < 240) {
    const int t0 = dir ? (T_ - 1) : 0;
    hxs[xoff] = x[((size_t)(b0 + xb) * T_ + t0) * D_ + xd];
  }
  __syncthreads();

  const int ef = 33 * e;                         // f4 base of my k-chunk
  float* swp = scr + wv * 2336 + jl * 72 + e;        // writer base: +g*584+i*9
  const float* srd = scr + wv * 2336 + jl * 72 + e * 9;  // reader: +g*584+k
  const int hoff = 132 * (2 + (j >> 4)) + 16 * e + ((32 + j) & 15);
  float* __restrict__ gp = g_h1 + ((size_t)(b0 + e) * T_) * 192
                                + (size_t)dir * 96 + j;

  for (int s = 0; s < T_; ++s) {
    const int t   = dir ? (T_ - 1 - s) : s;
    const int cur = s & 1, nxt = cur ^ 1;
    float xn = 0.0f;
    if (tid < 240 && s + 1 < T_) {
      const int tn = dir ? (t - 1) : (t + 1);
      xn = x[((size_t)(b0 + xb) * T_ + tn) * D_ + xd];
    }
    const float4* hb = (const float4*)(hxs + cur * 1056);
    float aI0=0.f,aI1=0.f,aI2=0.f,aI3=0.f,aI4=0.f,aI5=0.f,aI6=0.f,aI7=0.f;
    float aF0=0.f,aF1=0.f,aF2=0.f,aF3=0.f,aF4=0.f,aF5=0.f,aF6=0.f,aF7=0.f;
    float aG0=0.f,aG1=0.f,aG2=0.f,aG3=0.f,aG4=0.f,aG5=0.f,aG6=0.f,aG7=0.f;
    float aO0=0.f,aO1=0.f,aO2=0.f,aO3=0.f,aO4=0.f,aO5=0.f,aO6=0.f,aO7=0.f;
#define FB1(i) {                                                              \
    float4 v0 = hb[ef +  0 + i]; float4 v1 = hb[ef +  4 + i];                 \
    float4 v2 = hb[ef +  8 + i]; float4 v3 = hb[ef + 12 + i];                 \
    float4 v4 = hb[ef + 16 + i]; float4 v5 = hb[ef + 20 + i];                 \
    float4 v6 = hb[ef + 24 + i]; float4 v7 = hb[ef + 28 + i];                 \
    FMAROW(aI0, wA##i, v0) FMAROW(aF0, wB##i, v0)                             \
    FMAROW(aG0, wC##i, v0) FMAROW(aO0, wD##i, v0)                             \
    FMAROW(aI1, wA##i, v1) FMAROW(aF1, wB##i, v1)                             \
    FMAROW(aG1, wC##i, v1) FMAROW(aO1, wD##i, v1)                             \
    FMAROW(aI2, wA##i, v2) FMAROW(aF2, wB##i, v2)                             \
    FMAROW(aG2, wC##i, v2) FMAROW(aO2, wD##i, v2)                             \
    FMAROW(aI3, wA##i, v3) FMAROW(aF3, wB##i, v3)                             \
    FMAROW(aG3, wC##i, v3) FMAROW(aO3, wD##i, v3)                             \
    FMAROW(aI4, wA##i, v4) FMAROW(aF4, wB##i, v4)                             \
    FMAROW(aG4, wC##i, v4) FMAROW(aO4, wD##i, v4)                             \
    FMAROW(aI5, wA##i, v5) FMAROW(aF5, wB##i, v5)                             \
    FMAROW(aG5, wC##i, v5) FMAROW(aO5, wD##i, v5)                             \
    FMAROW(aI6, wA##i, v6) FMAROW(aF6, wB##i, v6)                             \
    FMAROW(aG6, wC##i, v6) FMAROW(aO6, wD##i, v6)                             \
    FMAROW(aI7, wA##i, v7) FMAROW(aF7, wB##i, v7)                             \
    FMAROW(aG7, wC##i, v7) FMAROW(aO7, wD##i, v7) }
    FB1(0) FB1(1) FB1(2) FB1(3)
#undef FB1
    // wave-internal reduction, scalar b32 (bank-clean by construction).
    swp[0*584 + 0*9] = aI0; swp[0*584 + 1*9] = aI1;
    swp[0*584 + 2*9] = aI2; swp[0*584 + 3*9] = aI3;
    swp[0*584 + 4*9] = aI4; swp[0*584 + 5*9] = aI5;
    swp[0*584 + 6*9] = aI6; swp[0*584 + 7*9] = aI7;
    swp[1*584 + 0*9] = aF0; swp[1*584 + 1*9] = aF1;
    swp[1*584 + 2*9] = aF2; swp[1*584 + 3*9] = aF3;
    swp[1*584 + 4*9] = aF4; swp[1*584 + 5*9] = aF5;
    swp[1*584 + 6*9] = aF6; swp[1*584 + 7*9] = aF7;
    swp[2*584 + 0*9] = aG0; swp[2*584 + 1*9] = aG1;
    swp[2*584 + 2*9] = aG2; swp[2*584 + 3*9] = aG3;
    swp[2*584 + 4*9] = aG4; swp[2*584 + 5*9] = aG5;
    swp[2*584 + 6*9] = aG6; swp[2*584 + 7*9] = aG7;
    swp[3*584 + 0*9] = aO0; swp[3*584 + 1*9] = aO1;
    swp[3*584 + 2*9] = aO2; swp[3*584 + 3*9] = aO3;
    swp[3*584 + 4*9] = aO4; swp[3*584 + 5*9] = aO5;
    swp[3*584 + 6*9] = aO6; swp[3*584 + 7*9] = aO7;
    {
      float gi = bias_i + srd[0*584+0] + srd[0*584+1] + srd[0*584+2]
               + srd[0*584+3] + srd[0*584+4] + srd[0*584+5]
               + srd[0*584+6] + srd[0*584+7];
      float gf = bias_f + srd[1*584+0] + srd[1*584+1] + srd[1*584+2]
               + srd[1*584+3] + srd[1*584+4] + srd[1*584+5]
               + srd[1*584+6] + srd[1*584+7];
      float gg = bias_g + srd[2*584+0] + srd[2*584+1] + srd[2*584+2]
               + srd[2*584+3] + srd[2*584+4] + srd[2*584+5]
               + srd[2*584+6] + srd[2*584+7];
      float go = bias_o + srd[3*584+0] + srd[3*584+1] + srd[3*584+2]
               + srd[3*584+3] + srd[3*584+4] + srd[3*584+5]
               + srd[3*584+6] + srd[3*584+7];
      float iv = fast_sigmoid(gi);
      float fv = fast_sigmoid(gf);
      float ov = fast_sigmoid(go);
      c_state = fv * c_state + iv * fast_tanh(gg);
      float h = ov * fast_tanh(c_state);
      hxs[nxt * 1056 + hoff] = h;                // my cell = (unit j, batch e)
      gp[(size_t)t * 192] = h;
    }
    if (tid < 240 && s + 1 < T_) hxs[nxt * 1056 + xoff] = xn;
    BAR_LGKM();
  }
}

// ---------------------------------------------------------------------------
// Layer 2 forward scan: g_h1 (B,T,192) -> g_h2f (B,64).  [R1 structure: best
// measured ~800us. The R5 wave-internal variant regressed: only 16/64 lanes
// were updaters but all 16 waves issued the masked update sequence.]
// grid 256: 4 batch/block. 1024 threads = (gate-PAIR jj = tid%128 owning rows
// jj and jj+128, k-eighth e = tid/128). gbuf stride 33 (measured clean).
// v[256]: [0:192)=h1_t, [192:256)=h2_{t-1}. Barriers: BAR_LGKM.
// ---------------------------------------------------------------------------
__global__ __launch_bounds__(1024, 4)
void lstm2f_kernel(const float* __restrict__ Wih, const float* __restrict__ Whh,
                   const float* __restrict__ bih, const float* __restrict__ bhh)
{
  const int tid = threadIdx.x;
  const int b0  = blockIdx.x * 4;
  const int jj  = tid % 128;                     // pair rows jj, jj+128
  const int e   = tid / 128;                     // k-eighth (wave-uniform)

  __shared__ __align__(16) float hx[4][256];     // [b][0:192 h1 | 192:256 h2prev]
  __shared__ float gbuf[G2_ * 33];               // [row][b*8+e], stride 33

  float4 w0,w1,w2,w3,w4,w5,w6,w7,w8,w9,w10,w11,w12,w13,w14,w15;
  {
    const float4* wa = (e < 6) ? (const float4*)(Wih + jj * 192 + 32 * e)
                               : (const float4*)(Whh + jj * H2_ + 32 * (e - 6));
    w0 = wa[0];  w1 = wa[1];  w2 = wa[2];  w3 = wa[3];
    w4 = wa[4];  w5 = wa[5];  w6 = wa[6];  w7 = wa[7];
    const float4* wb = (e < 6) ? (const float4*)(Wih + (jj + 128) * 192 + 32 * e)
                               : (const float4*)(Whh + (jj + 128) * H2_ + 32 * (e - 6));
    w8  = wb[0]; w9  = wb[1]; w10 = wb[2]; w11 = wb[3];
    w12 = wb[4]; w13 = wb[5]; w14 = wb[6]; w15 = wb[7];
  }

  const int uj = tid & 63;                       // updaters: tid < 256
  const int ub = (tid >> 6) & 3;
  const float bias_i = bih[uj      ] + bhh[uj      ];
  const float bias_f = bih[uj +  64] + bhh[uj +  64];
  const float bias_g = bih[uj + 128] + bhh[uj + 128];
  const float bias_o = bih[uj + 192] + bhh[uj + 192];
  float c_state = 0.0f;

  for (int i = tid; i < 4 * 256; i += 1024) (&hx[0][0])[i] = 0.0f;
  __syncthreads();
  const int pb = tid / 96;                       // h1 stagers: tid < 384
  const int pj = tid - pb * 96;
  if (tid < 384) {
    *(float2*)&hx[pb][pj * 2] =
        *(const float2*)&g_h1[((size_t)(b0 + pb) * T_ + 0) * 192 + pj * 2];
  }
  __syncthreads();

  const int eoff = e * 8;
  const float4* hx4 = (const float4*)(&hx[0][0]);

  for (int s = 0; s < T_; ++s) {
    float2 pre = make_float2(0.0f, 0.0f);
    if (tid < 384 && s + 1 < T_) {
      pre = *(const float2*)&g_h1[((size_t)(b0 + pb) * T_ + (s + 1)) * 192 + pj * 2];
    }
    float accA0=0.f, accA1=0.f, accA2=0.f, accA3=0.f;
    float accB0=0.f, accB1=0.f, accB2=0.f, accB3=0.f;
#define FB2(i, k) {                                                           \
    float4 v0 = hx4[0*64 + eoff + i]; float4 v1 = hx4[1*64 + eoff + i];       \
    float4 v2 = hx4[2*64 + eoff + i]; float4 v3 = hx4[3*64 + eoff + i];       \
    FMAROW(accA0, w##i, v0) FMAROW(accB0, w##k, v0)                           \
    FMAROW(accA1, w##i, v1) FMAROW(accB1, w##k, v1)                           \
    FMAROW(accA2, w##i, v2) FMAROW(accB2, w##k, v2)                           \
    FMAROW(accA3, w##i, v3) FMAROW(accB3, w##k, v3) }
    FB2(0,8) FB2(1,9) FB2(2,10) FB2(3,11)
    FB2(4,12) FB2(5,13) FB2(6,14) FB2(7,15)
#undef FB2
    {
      const int ga = jj * 33 + e;                // lanes: jj consecutive -> 2-way
      gbuf[ga +  0] = accA0; gbuf[ga +  8] = accA1;
      gbuf[ga + 16] = accA2; gbuf[ga + 24] = accA3;
      const int gbB = (jj + 128) * 33 + e;
      gbuf[gbB +  0] = accB0; gbuf[gbB +  8] = accB1;
      gbuf[gbB + 16] = accB2; gbuf[gbB + 24] = accB3;
    }
    BAR_LGKM();
    if (tid < 384 && s + 1 < T_) *(float2*)&hx[pb][pj * 2] = pre;
    if (tid < 256) {
      const int ro = ub * 8;
      float gi = bias_i, gf = bias_f, gg = bias_g, go = bias_o;
#pragma unroll
      for (int ee = 0; ee < 8; ++ee) {
        gi += gbuf[(uj      ) * 33 + ro + ee];
        gf += gbuf[(uj +  64) * 33 + ro + ee];
        gg += gbuf[(uj + 128) * 33 + ro + ee];
        go += gbuf[(uj + 192) * 33 + ro + ee];
      }
      float iv = fast_sigmoid(gi), fv = fast_sigmoid(gf), ov = fast_sigmoid(go);
      c_state = fv * c_state + iv * fast_tanh(gg);
      float h = ov * fast_tanh(c_state);
      hx[ub][192 + uj] = h;
      if (s == T_ - 1) g_h2f[(b0 + ub) * H2_ + uj] = h;
    }
    BAR_LGKM();
  }
}

// ---------------------------------------------------------------------------
// Tail: layer-2 backward (ONE step from zero state on h1[:,T-1,:]) + dense
// head. grid 128 x 256 threads, 8 batch/block. (negligible runtime)
// ---------------------------------------------------------------------------
__global__ __launch_bounds__(256)
void tail_kernel(const float* __restrict__ Wih, const float* __restrict__ bih,
                 const float* __restrict__ bhh,
                 const float* __restrict__ W1, const float* __restrict__ b1,
                 const float* __restrict__ W2, const float* __restrict__ b2,
                 float* __restrict__ out)
{
  const int tid = threadIdx.x;
  const int b0  = blockIdx.x * 8;

  __shared__ __align__(16) float hl[8][192];    // h1 at t = T-1
  __shared__ float gb[G2_ * 9];
  __shared__ __align__(16) float last[8][128];  // [h2f | h2b]
  __shared__ float db[8][32];

  for (int i = tid; i < 8 * 96; i += 256) {
    int bb = i / 96, jj = i - (i / 96) * 96;
    *(float2*)&hl[bb][jj * 2] =
        *(const float2*)&g_h1[((size_t)(b0 + bb) * T_ + (T_ - 1)) * 192 + jj * 2];
  }
  for (int i = tid; i < 8 * 64; i += 256) {
    int bb = i >> 6, jj = i & 63;
    last[bb][jj] = g_h2f[(b0 + bb) * H2_ + jj];
  }
  __syncthreads();

  {
    const int gg_ = tid;
    const float* wr = Wih + gg_ * 192;
    const float bias = bih[gg_] + bhh[gg_];
    float acc[8];
#pragma unroll
    for (int b = 0; b < 8; ++b) acc[b] = bias;
#pragma unroll 4
    for (int qq = 0; qq < 48; ++qq) {
      float4 wv = *(const float4*)&wr[qq * 4];
#pragma unroll
      for (int b = 0; b < 8; ++b) {
        float4 v = *(const float4*)&hl[b][qq * 4];
        acc[b] = fmaf(wv.x, v.x, acc[b]);
        acc[b] = fmaf(wv.y, v.y, acc[b]);
        acc[b] = fmaf(wv.z, v.z, acc[b]);
        acc[b] = fmaf(wv.w, v.w, acc[b]);
      }
    }
#pragma unroll
    for (int b = 0; b < 8; ++b) gb[gg_ * 9 + b] = acc[b];
  }
  __syncthreads();

  for (int p = tid; p < 512; p += 256) {
    int jj = p & 63, bb = p >> 6;
    float gi = gb[(jj      ) * 9 + bb];
    float gg = gb[(jj + 128) * 9 + bb];
    float go = gb[(jj + 192) * 9 + bb];
    float c  = fast_sigmoid(gi) * fast_tanh(gg);
    float h  = fast_sigmoid(go) * fast_tanh(c);
    last[bb][64 + jj] = h;
  }
  __syncthreads();

  {
    int u = tid & 31, bb = tid >> 5;
    const float* wr1 = W1 + u * 128;
    float a = b1[u];
#pragma unroll
    for (int qq = 0; qq < 32; ++qq) {
      float4 wv = *(const float4*)&wr1[qq * 4];
      float4 v  = *(const float4*)&last[bb][qq * 4];
      a = fmaf(wv.x, v.x, a); a = fmaf(wv.y, v.y, a);
      a = fmaf(wv.z, v.z, a); a = fmaf(wv.w, v.w, a);
    }
    db[bb][u] = fmaxf(a, 0.0f);
  }
  __syncthreads();

  if (tid < 8) {
    float a = b2[0];
#pragma unroll
    for (int u2 = 0; u2 < 32; ++u2) a = fmaf(db[tid][u2], W2[u2], a);
    out[b0 + tid] = a;
  }
}

extern "C" void kernel_launch(void* const* d_in, const int* in_sizes, int n_in,
                              void* d_out, int out_size, void* d_ws, size_t ws_size,
                              hipStream_t stream)
{
  const float* x     = (const float*)d_in[0];
  const float* Wih1f = (const float*)d_in[1];
  const float* Whh1f = (const float*)d_in[2];
  const float* bih1f = (const float*)d_in[3];
  const float* bhh1f = (const float*)d_in[4];
  const float* Wih1b = (const float*)d_in[5];
  const float* Whh1b = (const float*)d_in[6];
  const float* bih1b = (const float*)d_in[7];
  const float* bhh1b = (const float*)d_in[8];
  const float* Wih2f = (const float*)d_in[9];
  const float* Whh2f = (const float*)d_in[10];
  const float* bih2f = (const float*)d_in[11];
  const float* bhh2f = (const float*)d_in[12];
  const float* Wih2b = (const float*)d_in[13];
  /* Whh2b (d_in[14]) unused: layer-2 backward at t=T-1 is one step from h=0 */
  const float* bih2b = (const float*)d_in[15];
  const float* bhh2b = (const float*)d_in[16];
  const float* W1    = (const float*)d_in[17];
  const float* b1    = (const float*)d_in[18];
  const float* W2    = (const float*)d_in[19];
  const float* b2    = (const float*)d_in[20];

  (void)d_ws; (void)ws_size; (void)in_sizes; (void)n_in; (void)out_size;

  lstm1_kernel<<<dim3(128, 2), 768, 0, stream>>>(
      x, Wih1f, Whh1f, bih1f, bhh1f, Wih1b, Whh1b, bih1b, bhh1b);
  lstm2f_kernel<<<256, 1024, 0, stream>>>(
      Wih2f, Whh2f, bih2f, bhh2f);
  tail_kernel<<<128, 256, 0, stream>>>(
      Wih2b, bih2b, bhh2b, W1, b1, W2, b2, (float*)d_out);
}